// Round 14
// baseline (664.525 us; speedup 1.0000x reference)
//
#include <hip/hip_runtime.h>
#include <hip/hip_fp16.h>
#include <math.h>

// Problem constants (from reference)
#define BS    8
#define NE    4800
#define NN    4981
#define CIN   3
#define HD    128      // H
#define DBLK  6        // D processor blocks
#define NEDGE 153600   // BS*EPG
#define NTOT  38400    // BS*NE (graph nodes)
#define NMESH (BS*NN)  // 39848 mesh rows
#define NNP   5120     // NN padded to 20*256 for scan
#define EM    128      // edge-kernel tile rows

// transposed decoder-weight table offsets (floats)
#define UW1T  0
#define UB1T  512
#define UW2T  1024
#define UB2T  3072
#define UW3T  3584
#define ULNGT 5632
#define ULNBT 6144
#define DWT_N 6656

typedef _Float16 f16;
typedef _Float16 f16x8 __attribute__((ext_vector_type(8)));
typedef float f32x4 __attribute__((ext_vector_type(4)));

__device__ __forceinline__ float lrelu(float x) { return x >= 0.0f ? x : 0.2f * x; }

// ---------------------------------------------------------------------------
// K0: hv0 = ln(mlp(enc_clnb_row, enc_ew1..3), enc_elng, enc_elnb)
// Conv encoder + LayerNorm over size-1 axis collapses exactly to enc_clnb.
// ---------------------------------------------------------------------------
__global__ __launch_bounds__(128)
void enc_const_kernel(const float* __restrict__ clnb,
                      const float* __restrict__ ew1, const float* __restrict__ eb1,
                      const float* __restrict__ ew2, const float* __restrict__ eb2,
                      const float* __restrict__ ew3,
                      const float* __restrict__ g, const float* __restrict__ b,
                      float* __restrict__ hv0) {
    __shared__ float s1[HD], s2[HD], s3[HD];
    int j = threadIdx.x;
    float a = eb1[j];
    for (int c = 0; c < CIN; ++c) a += clnb[c] * ew1[c * HD + j];
    s1[j] = lrelu(a);
    __syncthreads();
    a = eb2[j];
    for (int k = 0; k < HD; ++k) a += s1[k] * ew2[k * HD + j];
    s2[j] = lrelu(a);
    __syncthreads();
    a = 0.0f;
    for (int k = 0; k < HD; ++k) a += s2[k] * ew3[k * HD + j];
    s3[j] = a;
    __syncthreads();
    float m = 0.0f;
    for (int k = 0; k < HD; ++k) m += s3[k];
    m *= (1.0f / HD);
    float v = 0.0f;
    for (int k = 0; k < HD; ++k) { float d = s3[k] - m; v += d * d; }
    v *= (1.0f / HD);
    float rs = 1.0f / sqrtf(v + 1e-5f);
    hv0[j] = (s3[j] - m) * rs * g[j] + b[j];
}

// d=0 edge message: m0 = ln(mlp([h0;h0]), elng0, elnb0). Exact identity:
// at d=0 all node rows equal h0 -> every edge message equals m0 and
// aggr[n] = deg(n) * m0.
__global__ __launch_bounds__(128)
void msg0_kernel(const float* __restrict__ hv0,
                 const float* __restrict__ ew1, const float* __restrict__ eb1,
                 const float* __restrict__ ew2, const float* __restrict__ eb2,
                 const float* __restrict__ ew3,
                 const float* __restrict__ g, const float* __restrict__ b,
                 float* __restrict__ m0) {
    __shared__ float s1[HD], s2[HD], s3[HD];
    int j = threadIdx.x;
    float a = eb1[j];
    for (int k = 0; k < HD; ++k) a += hv0[k] * (ew1[k * HD + j] + ew1[(k + HD) * HD + j]);
    s1[j] = lrelu(a);
    __syncthreads();
    a = eb2[j];
    for (int k = 0; k < HD; ++k) a += s1[k] * ew2[k * HD + j];
    s2[j] = lrelu(a);
    __syncthreads();
    a = 0.0f;
    for (int k = 0; k < HD; ++k) a += s2[k] * ew3[k * HD + j];
    s3[j] = a;
    __syncthreads();
    float m = 0.0f;
    for (int k = 0; k < HD; ++k) m += s3[k];
    m *= (1.0f / HD);
    float v = 0.0f;
    for (int k = 0; k < HD; ++k) { float d = s3[k] - m; v += d * d; }
    v *= (1.0f / HD);
    float rs = 1.0f / sqrtf(v + 1e-5f);
    m0[j] = (s3[j] - m) * rs * g[j] + b[j];
}

// Broadcast hv0 (fp32) to all NTOT node rows as f16
__global__ __launch_bounds__(256)
void init_h16_kernel(f16* __restrict__ h, const float* __restrict__ hv0, int n8) {
    __shared__ f16 v[HD];
    if (threadIdx.x < HD) v[threadIdx.x] = (f16)hv0[threadIdx.x];
    __syncthreads();
    for (int i = blockIdx.x * blockDim.x + threadIdx.x; i < n8; i += gridDim.x * blockDim.x)
        ((uint4*)h)[i] = ((const uint4*)v)[i & 15];
}

// ---------------------------------------------------------------------------
// Convert + transpose processor weights to f16 Wt[n][k] layout.
// ---------------------------------------------------------------------------
__global__ __launch_bounds__(256)
void conv_weights_kernel(const float* __restrict__ ew1, const float* __restrict__ ew2,
                         const float* __restrict__ ew3,
                         const float* __restrict__ nw1, const float* __restrict__ nw2,
                         const float* __restrict__ nw3, f16* __restrict__ wbuf) {
    int b = blockIdx.x;        // 0..47
    int d = b >> 3, m = b & 7;
    const float* src;
    switch (m) {
        case 0: src = ew1 + (size_t)d * 2 * HD * HD; break;
        case 1: src = ew1 + (size_t)d * 2 * HD * HD + HD * HD; break;
        case 2: src = ew2 + (size_t)d * HD * HD; break;
        case 3: src = ew3 + (size_t)d * HD * HD; break;
        case 4: src = nw1 + (size_t)d * 2 * HD * HD; break;
        case 5: src = nw1 + (size_t)d * 2 * HD * HD + HD * HD; break;
        case 6: src = nw2 + (size_t)d * HD * HD; break;
        default: src = nw3 + (size_t)d * HD * HD; break;
    }
    f16* out = wbuf + (size_t)b * HD * HD;
    for (int idx = threadIdx.x; idx < HD * HD; idx += 256) {
        int n = idx >> 7, k = idx & 127;
        out[idx] = (f16)src[k * HD + n];   // Wt[n][k] = W[k][n]
    }
}

// Transpose decoder per-channel weights to channel-major (lane-coalesced).
__global__ __launch_bounds__(256)
void conv_dec_weights(const float* __restrict__ uw1, const float* __restrict__ ub1,
                      const float* __restrict__ uw2, const float* __restrict__ ub2,
                      const float* __restrict__ uw3, const float* __restrict__ ulng,
                      const float* __restrict__ ulnb, float* __restrict__ dwt) {
    int tid = threadIdx.x;
    for (int idx = tid; idx < 512; idx += 256) {
        int o = idx >> 7, c = idx & 127;
        dwt[UW1T + idx] = uw1[c * 4 + o];
        dwt[UB1T + idx] = ub1[c * 4 + o];
        dwt[UB2T + idx] = ub2[c * 4 + o];
        dwt[ULNGT + idx] = ulng[c * 4 + o];
        dwt[ULNBT + idx] = ulnb[c * 4 + o];
    }
    for (int idx = tid; idx < 2048; idx += 256) {
        int io = idx >> 7, c = idx & 127;
        dwt[UW2T + idx] = uw2[c * 16 + io];
        dwt[UW3T + idx] = uw3[c * 16 + io];
    }
}

// ---------------------------------------------------------------------------
// CSR build helpers (counting sort). Edge graph (by dest) + mesh (by conn).
// ---------------------------------------------------------------------------
__global__ __launch_bounds__(256)
void csr_hist(const int* __restrict__ key, int* __restrict__ deg, int n) {
    int e = blockIdx.x * 256 + threadIdx.x;
    if (e < n) atomicAdd(&deg[key[e]], 1);
}

__global__ __launch_bounds__(256)
void csr_scan1(const int* __restrict__ deg, int* __restrict__ rowptr,
               int* __restrict__ bsum) {
    __shared__ int s[256];
    int i = blockIdx.x * 256 + threadIdx.x;
    int v = deg[i];
    s[threadIdx.x] = v;
    __syncthreads();
    for (int off = 1; off < 256; off <<= 1) {
        int t = (threadIdx.x >= off) ? s[threadIdx.x - off] : 0;
        __syncthreads();
        s[threadIdx.x] += t;
        __syncthreads();
    }
    rowptr[i] = s[threadIdx.x] - v;          // exclusive
    if (threadIdx.x == 255) bsum[blockIdx.x] = s[255];
}

__global__ __launch_bounds__(256)
void csr_scan2(int* __restrict__ bsum, int nb) {
    __shared__ int s[256];
    int v = (threadIdx.x < nb) ? bsum[threadIdx.x] : 0;
    s[threadIdx.x] = v;
    __syncthreads();
    for (int off = 1; off < 256; off <<= 1) {
        int t = (threadIdx.x >= off) ? s[threadIdx.x - off] : 0;
        __syncthreads();
        s[threadIdx.x] += t;
        __syncthreads();
    }
    if (threadIdx.x < nb) bsum[threadIdx.x] = s[threadIdx.x] - v;   // exclusive
}

__global__ __launch_bounds__(256)
void csr_scan3(int* __restrict__ rowptr, const int* __restrict__ bsum) {
    int i = blockIdx.x * 256 + threadIdx.x;
    rowptr[i] += bsum[blockIdx.x];
}

// Edge scatter: store (dest, src) sorted by dest
__global__ __launch_bounds__(256)
void csr_scatter(const int* __restrict__ dest, const int* __restrict__ srcv,
                 const int* __restrict__ rowptr, int* __restrict__ cursor,
                 int* __restrict__ dsorted, int* __restrict__ ssorted) {
    int e = blockIdx.x * 256 + threadIdx.x;
    int d = dest[e];
    int pos = rowptr[d] + atomicAdd(&cursor[d], 1);
    dsorted[pos] = d;
    ssorted[pos] = srcv[e];
}

// Mesh scatter: store slot index (e*4+o) sorted by mesh node conn[e*4+o]
__global__ __launch_bounds__(256)
void mesh_scatter(const int* __restrict__ conn, const int* __restrict__ mrow,
                  int* __restrict__ mcur, int* __restrict__ mslot, int n) {
    int idx = blockIdx.x * 256 + threadIdx.x;
    if (idx < n) {
        int nd = conn[idx];
        int pos = mrow[nd] + atomicAdd(&mcur[nd], 1);
        mslot[pos] = idx;
    }
}

// ---------------------------------------------------------------------------
// Shared GEMM helpers. MFMA 16x16x32; wave w: rows (w>>1)*32, cols (w&1)*64,
// 2x4 grid of tiles. A[m=lane&15][k=quad*8+j], C/D col=lane&15, row=quad*4+reg
// (guide-verified).
// ---------------------------------------------------------------------------
template <int NT>
__device__ __forceinline__ void stage_w(const f16* __restrict__ Wg, f16 (*Bt)[HD + 8],
                                        int tid) {
    #pragma unroll
    for (int t = 0; t < 2048 / NT; ++t) {
        int idx = tid + t * NT;             // 16B chunks of 128x128 f16
        int r = idx >> 4, c = (idx & 15) * 8;
        *(uint4*)(&Bt[r][c]) = *(const uint4*)(Wg + (size_t)r * HD + c);
    }
}

__device__ __forceinline__ void mfma_pass(const f16 (*A)[HD + 8], const f16 (*Bt)[HD + 8],
                                          int rt_base, int ct_base, int ln, int quad,
                                          f32x4 acc[2][4]) {
    #pragma unroll
    for (int ks = 0; ks < 4; ++ks) {
        int kb = ks * 32 + quad * 8;
        f16x8 a0 = *(const f16x8*)(&A[rt_base + ln][kb]);
        f16x8 a1 = *(const f16x8*)(&A[rt_base + 16 + ln][kb]);
        #pragma unroll
        for (int c = 0; c < 4; ++c) {
            f16x8 b = *(const f16x8*)(&Bt[ct_base + c * 16 + ln][kb]);
            acc[0][c] = __builtin_amdgcn_mfma_f32_16x16x32_f16(a0, b, acc[0][c], 0, 0, 0);
            acc[1][c] = __builtin_amdgcn_mfma_f32_16x16x32_f16(a1, b, acc[1][c], 0, 0, 0);
        }
    }
}

// ---------------------------------------------------------------------------
// Edge kernel (d>=1), dest-sorted, M=128 tile, 512 threads (8 waves):
// act1 = lrelu(P1[d]+P2[s]+b1), W2/W3 passes, LN, plain f16 store to msg.
// Full-K Bt staging, 2 blocks/CU — measured local optimum (round 10: 642 µs
// total; half-K 3-blocks/CU variant regressed to 664 µs in round 11, barrier
// overhead > occupancy gain; M=64 3-blocks/CU was no better in rounds 7-9;
// cross-kernel producer-consumer fusion hung in round 13).
// ---------------------------------------------------------------------------
__global__ __launch_bounds__(512, 4)
void gn_edge(const f16* __restrict__ P1, const f16* __restrict__ P2,
             const int* __restrict__ dsorted, const int* __restrict__ ssorted,
             const f16* __restrict__ W2, const f16* __restrict__ W3,
             const float* __restrict__ b1, const float* __restrict__ b2,
             const float* __restrict__ g, const float* __restrict__ bln,
             f16* __restrict__ msg) {
    __shared__ __align__(16) f16 As[EM][HD + 8];
    __shared__ __align__(16) f16 Bt[HD][HD + 8];
    __shared__ float red[EM][2][2];
    __shared__ int dS[EM], sS[EM];

    const int tid = threadIdx.x;
    const int base = blockIdx.x * EM;
    const int wave = tid >> 6, lane = tid & 63;
    const int ln = lane & 15, quad = lane >> 4;
    const int rt_base = (wave >> 1) * 32;     // 0,32,64,96
    const int ct_base = (wave & 1) * 64;
    const int half = wave & 1;

    if (tid < EM) dS[tid] = dsorted[base + tid];
    else if (tid < 2 * EM) sS[tid - EM] = ssorted[base + tid - EM];
    __syncthreads();

    stage_w<512>(W2, Bt, tid);
    #pragma unroll
    for (int t = 0; t < 4; ++t) {
        int idx = tid + t * 512;            // 0..2047
        int r = idx >> 4, c = (idx & 15) * 8;
        f16x8 p1 = *(const f16x8*)(P1 + (size_t)dS[r] * HD + c);
        f16x8 p2 = *(const f16x8*)(P2 + (size_t)sS[r] * HD + c);
        float4 ba = *(const float4*)(b1 + c);
        float4 bb = *(const float4*)(b1 + c + 4);
        f16x8 o;
        o[0] = (f16)lrelu((float)p1[0] + (float)p2[0] + ba.x);
        o[1] = (f16)lrelu((float)p1[1] + (float)p2[1] + ba.y);
        o[2] = (f16)lrelu((float)p1[2] + (float)p2[2] + ba.z);
        o[3] = (f16)lrelu((float)p1[3] + (float)p2[3] + ba.w);
        o[4] = (f16)lrelu((float)p1[4] + (float)p2[4] + bb.x);
        o[5] = (f16)lrelu((float)p1[5] + (float)p2[5] + bb.y);
        o[6] = (f16)lrelu((float)p1[6] + (float)p2[6] + bb.z);
        o[7] = (f16)lrelu((float)p1[7] + (float)p2[7] + bb.w);
        *(f16x8*)(&As[r][c]) = o;
    }
    __syncthreads();

    f32x4 acc[2][4];

    // ---- Layer 2
    #pragma unroll
    for (int c = 0; c < 4; ++c) {
        float bj = b2[ct_base + c * 16 + ln];
        f32x4 bb = {bj, bj, bj, bj};
        acc[0][c] = bb; acc[1][c] = bb;
    }
    mfma_pass(As, Bt, rt_base, ct_base, ln, quad, acc);
    __syncthreads();
    stage_w<512>(W3, Bt, tid);
    #pragma unroll
    for (int i = 0; i < 2; ++i)
        #pragma unroll
        for (int c = 0; c < 4; ++c)
            #pragma unroll
            for (int r = 0; r < 4; ++r)
                As[rt_base + i * 16 + quad * 4 + r][ct_base + c * 16 + ln] =
                    (f16)lrelu(acc[i][c][r]);
    __syncthreads();

    // ---- Layer 3
    #pragma unroll
    for (int c = 0; c < 4; ++c) { f32x4 z = {0,0,0,0}; acc[0][c] = z; acc[1][c] = z; }
    mfma_pass(As, Bt, rt_base, ct_base, ln, quad, acc);

    // ---- LayerNorm stats
    #pragma unroll
    for (int i = 0; i < 2; ++i)
        #pragma unroll
        for (int r = 0; r < 4; ++r) {
            float s = acc[i][0][r] + acc[i][1][r] + acc[i][2][r] + acc[i][3][r];
            float q = acc[i][0][r] * acc[i][0][r] + acc[i][1][r] * acc[i][1][r] +
                      acc[i][2][r] * acc[i][2][r] + acc[i][3][r] * acc[i][3][r];
            s += __shfl_xor(s, 1); q += __shfl_xor(q, 1);
            s += __shfl_xor(s, 2); q += __shfl_xor(q, 2);
            s += __shfl_xor(s, 4); q += __shfl_xor(q, 4);
            s += __shfl_xor(s, 8); q += __shfl_xor(q, 8);
            if (ln == 0) {
                int row = rt_base + i * 16 + quad * 4 + r;
                red[row][half][0] = s;
                red[row][half][1] = q;
            }
        }
    __syncthreads();

    // ---- Epilogue: LN scale + plain f16 store to msg (sorted slot order)
    float gv[4], bv[4];
    #pragma unroll
    for (int c = 0; c < 4; ++c) {
        int col = ct_base + c * 16 + ln;
        gv[c] = g[col]; bv[c] = bln[col];
    }
    #pragma unroll
    for (int i = 0; i < 2; ++i)
        #pragma unroll
        for (int r = 0; r < 4; ++r) {
            int row = rt_base + i * 16 + quad * 4 + r;
            float s = red[row][0][0] + red[row][1][0];
            float q = red[row][0][1] + red[row][1][1];
            float m = s * (1.0f / HD);
            float var = q * (1.0f / HD) - m * m;
            float rs = 1.0f / sqrtf(var + 1e-5f);
            #pragma unroll
            for (int c = 0; c < 4; ++c) {
                int col = ct_base + c * 16 + ln;
                float v = (acc[i][c][r] - m) * rs * gv[c] + bv[c];
                msg[(size_t)(base + row) * HD + col] = (f16)v;
            }
        }
}

// ---------------------------------------------------------------------------
// Node kernel — single 64-row As buffer, h held in VGPRs during the aggr
// pass (L1 split passes reordered: aggr@W1b then h@W1a — commutative).
// rpS/dgS alias `red`. LDS 54.3 KB -> 3 blocks/CU.
// AGGR=0: aggr row = deg(n)*m0 (exact d=0 identity).
// AGGR=1: aggr row = fp32 sum of the node's contiguous msg rows (CSR).
// PROD: also emit P1/P2 for the next edge stage. In-place h16 update.
// ---------------------------------------------------------------------------
template <int AGGR, bool PROD>
__global__ __launch_bounds__(256, 3)
void gn_node(f16* __restrict__ h16, const f16* __restrict__ msg,
             const int* __restrict__ rowptr, const int* __restrict__ deg,
             const float* __restrict__ m0,
             const f16* __restrict__ W1a, const f16* __restrict__ W1b,
             const f16* __restrict__ W2, const f16* __restrict__ W3,
             const float* __restrict__ b1, const float* __restrict__ b2,
             const float* __restrict__ g, const float* __restrict__ bln,
             const f16* __restrict__ nW1a, const f16* __restrict__ nW1b,
             f16* __restrict__ P1, f16* __restrict__ P2) {
    __shared__ __align__(16) f16 As[64][HD + 8];
    __shared__ __align__(16) f16 Bt[HD][HD + 8];
    __shared__ float red[64][2][2];
    int* rpS = (int*)&red[0][0][0];   // alias: index staging only (pre-LN)
    int* dgS = rpS + 64;

    const int tid = threadIdx.x;
    const int base = blockIdx.x * 64;
    const int wave = tid >> 6, lane = tid & 63;
    const int ln = lane & 15, quad = lane >> 4;
    const int rt_base = (wave >> 1) * 32;
    const int ct_base = (wave & 1) * 64;
    const int half = wave & 1;

    if (tid < 64) {
        if (AGGR == 1) rpS[tid] = rowptr[base + tid];
        dgS[tid] = deg[base + tid];
    }
    __syncthreads();

    // ---- Stage: aggr -> As, h -> hreg (VGPRs)
    f16x8 hreg[4];
    #pragma unroll
    for (int t = 0; t < 4; ++t) {
        int idx = tid + t * 256;            // 0..1023
        int r = idx >> 4, c = (idx & 15) * 8;
        hreg[t] = *(const f16x8*)(h16 + (size_t)(base + r) * HD + c);
        if (AGGR == 0) {
            float sc = (float)dgS[r];
            f16x8 o;
            #pragma unroll
            for (int u = 0; u < 8; ++u) o[u] = (f16)(sc * m0[c + u]);
            *(f16x8*)(&As[r][c]) = o;
        } else {
            int rp = rpS[r], dg = dgS[r];
            float a[8] = {0, 0, 0, 0, 0, 0, 0, 0};
            for (int j = 0; j < dg; ++j) {
                f16x8 mv = *(const f16x8*)(msg + (size_t)(rp + j) * HD + c);
                #pragma unroll
                for (int u = 0; u < 8; ++u) a[u] += (float)mv[u];
            }
            f16x8 o;
            #pragma unroll
            for (int u = 0; u < 8; ++u) o[u] = (f16)a[u];
            *(f16x8*)(&As[r][c]) = o;
        }
    }
    stage_w<256>(W1b, Bt, tid);
    __syncthreads();

    f32x4 acc[2][4];
    #pragma unroll
    for (int c = 0; c < 4; ++c) {
        float bj = b1[ct_base + c * 16 + ln];
        f32x4 bb = {bj, bj, bj, bj};
        acc[0][c] = bb; acc[1][c] = bb;
    }
    mfma_pass(As, Bt, rt_base, ct_base, ln, quad, acc);   // aggr @ W1b
    __syncthreads();

    #pragma unroll
    for (int t = 0; t < 4; ++t) {
        int idx = tid + t * 256;
        int r = idx >> 4, c = (idx & 15) * 8;
        *(f16x8*)(&As[r][c]) = hreg[t];
    }
    stage_w<256>(W1a, Bt, tid);
    __syncthreads();
    mfma_pass(As, Bt, rt_base, ct_base, ln, quad, acc);   // + h @ W1a
    __syncthreads();

    stage_w<256>(W2, Bt, tid);
    #pragma unroll
    for (int i = 0; i < 2; ++i)
        #pragma unroll
        for (int c = 0; c < 4; ++c)
            #pragma unroll
            for (int r = 0; r < 4; ++r)
                As[rt_base + i * 16 + quad * 4 + r][ct_base + c * 16 + ln] =
                    (f16)lrelu(acc[i][c][r]);
    __syncthreads();

    #pragma unroll
    for (int c = 0; c < 4; ++c) {
        float bj = b2[ct_base + c * 16 + ln];
        f32x4 bb = {bj, bj, bj, bj};
        acc[0][c] = bb; acc[1][c] = bb;
    }
    mfma_pass(As, Bt, rt_base, ct_base, ln, quad, acc);   // act1 @ W2
    __syncthreads();
    stage_w<256>(W3, Bt, tid);
    #pragma unroll
    for (int i = 0; i < 2; ++i)
        #pragma unroll
        for (int c = 0; c < 4; ++c)
            #pragma unroll
            for (int r = 0; r < 4; ++r)
                As[rt_base + i * 16 + quad * 4 + r][ct_base + c * 16 + ln] =
                    (f16)lrelu(acc[i][c][r]);
    __syncthreads();

    #pragma unroll
    for (int c = 0; c < 4; ++c) { f32x4 z = {0,0,0,0}; acc[0][c] = z; acc[1][c] = z; }
    mfma_pass(As, Bt, rt_base, ct_base, ln, quad, acc);   // act2 @ W3

    // ---- LayerNorm stats (red now safe: rpS/dgS long dead)
    #pragma unroll
    for (int i = 0; i < 2; ++i)
        #pragma unroll
        for (int r = 0; r < 4; ++r) {
            float s = acc[i][0][r] + acc[i][1][r] + acc[i][2][r] + acc[i][3][r];
            float q = acc[i][0][r] * acc[i][0][r] + acc[i][1][r] * acc[i][1][r] +
                      acc[i][2][r] * acc[i][2][r] + acc[i][3][r] * acc[i][3][r];
            s += __shfl_xor(s, 1); q += __shfl_xor(q, 1);
            s += __shfl_xor(s, 2); q += __shfl_xor(q, 2);
            s += __shfl_xor(s, 4); q += __shfl_xor(q, 4);
            s += __shfl_xor(s, 8); q += __shfl_xor(q, 8);
            if (ln == 0) {
                int row = rt_base + i * 16 + quad * 4 + r;
                red[row][half][0] = s;
                red[row][half][1] = q;
            }
        }
    __syncthreads();

    float gv[4], bv[4];
    #pragma unroll
    for (int c = 0; c < 4; ++c) {
        int col = ct_base + c * 16 + ln;
        gv[c] = g[col]; bv[c] = bln[col];
    }
    #pragma unroll
    for (int i = 0; i < 2; ++i)
        #pragma unroll
        for (int r = 0; r < 4; ++r) {
            int row = rt_base + i * 16 + quad * 4 + r;
            float s = red[row][0][0] + red[row][1][0];
            float q = red[row][0][1] + red[row][1][1];
            float m = s * (1.0f / HD);
            float var = q * (1.0f / HD) - m * m;
            float rs = 1.0f / sqrtf(var + 1e-5f);
            #pragma unroll
            for (int c = 0; c < 4; ++c) {
                int col = ct_base + c * 16 + ln;
                float v = (acc[i][c][r] - m) * rs * gv[c] + bv[c];
                f16 hv = (f16)v;
                h16[(size_t)(base + row) * HD + col] = hv;
                if (PROD) As[row][col] = hv;    // h_new for P production
            }
        }

    if (PROD) {
        __syncthreads();                 // h_new in As visible
        stage_w<256>(nW1a, Bt, tid);
        __syncthreads();
        #pragma unroll
        for (int c = 0; c < 4; ++c) { f32x4 z = {0,0,0,0}; acc[0][c] = z; acc[1][c] = z; }
        mfma_pass(As, Bt, rt_base, ct_base, ln, quad, acc);
        #pragma unroll
        for (int i = 0; i < 2; ++i)
            #pragma unroll
            for (int c = 0; c < 4; ++c)
                #pragma unroll
                for (int r = 0; r < 4; ++r)
                    P1[(size_t)(base + rt_base + i * 16 + quad * 4 + r) * HD +
                       ct_base + c * 16 + ln] = (f16)acc[i][c][r];
        __syncthreads();
        stage_w<256>(nW1b, Bt, tid);
        __syncthreads();
        #pragma unroll
        for (int c = 0; c < 4; ++c) { f32x4 z = {0,0,0,0}; acc[0][c] = z; acc[1][c] = z; }
        mfma_pass(As, Bt, rt_base, ct_base, ln, quad, acc);
        #pragma unroll
        for (int i = 0; i < 2; ++i)
            #pragma unroll
            for (int c = 0; c < 4; ++c)
                #pragma unroll
                for (int r = 0; r < 4; ++r)
                    P2[(size_t)(base + rt_base + i * 16 + quad * 4 + r) * HD +
                       ct_base + c * 16 + ln] = (f16)acc[i][c][r];
    }
}

// ---------------------------------------------------------------------------
// Decoder stage 1: upsample MLP + LN(4) with channel-major (coalesced)
// transposed weights; LDS-staged wide stores to uval.
// ---------------------------------------------------------------------------
__global__ __launch_bounds__(256)
void dec_store_kernel(const f16* __restrict__ h, const float* __restrict__ dwt,
                      f16* __restrict__ uval) {
    __shared__ f16 ub[2][4][HD];
    int tid = threadIdx.x;
    int idx = blockIdx.x * 256 + tid;            // 0 .. NTOT*HD-1
    int c = idx & 127;
    int nl = tid >> 7;                           // 0..1
    float s = (float)h[idx];
    float u1[4], u2[4], u3[4];
    #pragma unroll
    for (int o = 0; o < 4; ++o)
        u1[o] = lrelu(s * dwt[UW1T + o * 128 + c] + dwt[UB1T + o * 128 + c]);
    #pragma unroll
    for (int o = 0; o < 4; ++o) {
        float a = dwt[UB2T + o * 128 + c];
        #pragma unroll
        for (int i = 0; i < 4; ++i) a += u1[i] * dwt[UW2T + (i * 4 + o) * 128 + c];
        u2[o] = lrelu(a);
    }
    #pragma unroll
    for (int o = 0; o < 4; ++o) {
        float a = 0.f;
        #pragma unroll
        for (int i = 0; i < 4; ++i) a += u2[i] * dwt[UW3T + (i * 4 + o) * 128 + c];
        u3[o] = a;
    }
    float m = 0.25f * (u3[0] + u3[1] + u3[2] + u3[3]);
    float var = 0.f;
    #pragma unroll
    for (int o = 0; o < 4; ++o) { float d = u3[o] - m; var += d * d; }
    var *= 0.25f;
    float rs = 1.0f / sqrtf(var + 1e-5f);
    #pragma unroll
    for (int o = 0; o < 4; ++o) {
        float val = (u3[o] - m) * rs * dwt[ULNGT + o * 128 + c] + dwt[ULNBT + o * 128 + c];
        ub[nl][o][c] = (f16)val;
    }
    __syncthreads();
    int nl2 = tid >> 7, rem = tid & 127;
    uint2 v = ((const uint2*)&ub[nl2][0][0])[rem];
    ((uint2*)(uval + (size_t)(blockIdx.x * 2 + nl2) * 4 * HD))[rem] = v;
}

// ---------------------------------------------------------------------------
// Decoder stage 2 (fused gather + output MLP): one wave per mesh row.
// ---------------------------------------------------------------------------
__global__ __launch_bounds__(256)
void dec_gather_out(const f16* __restrict__ uval,
                    const int* __restrict__ mrow, const int* __restrict__ mdeg,
                    const int* __restrict__ mslot,
                    const float* __restrict__ cw1, const float* __restrict__ cb1,
                    const float* __restrict__ cw2, const float* __restrict__ cb2,
                    const float* __restrict__ cw3,
                    float* __restrict__ o, int nrows) {
    int r = blockIdx.x * 4 + (threadIdx.x >> 6);
    if (r >= nrows) return;
    int lane = threadIdx.x & 63;
    int b = r / NN, n = r - b * NN;
    int rp = mrow[n], dg = mdeg[n];
    size_t boff = (size_t)b * NE * 4;
    float a0 = 0.f, a1 = 0.f;
    for (int j = 0; j < dg; ++j) {
        int slot = mslot[rp + j];
        const f16* up = uval + (boff + slot) * HD + lane * 2;
        a0 += (float)up[0];
        a1 += (float)up[1];
    }
    int c0 = lane * 2, c1 = lane * 2 + 1;
    float s[3];
    #pragma unroll
    for (int k = 0; k < 3; ++k)
        s[k] = a0 * cw1[c0 * 3 + k] + a1 * cw1[c1 * 3 + k];
    #pragma unroll
    for (int off = 32; off >= 1; off >>= 1) {
        s[0] += __shfl_down(s[0], off);
        s[1] += __shfl_down(s[1], off);
        s[2] += __shfl_down(s[2], off);
    }
    if (lane == 0) {
        float t1[3], t2[3];
        #pragma unroll
        for (int k = 0; k < 3; ++k) t1[k] = lrelu(s[k] + cb1[k]);
        #pragma unroll
        for (int k = 0; k < 3; ++k) {
            float a = cb2[k];
            #pragma unroll
            for (int q = 0; q < 3; ++q) a += t1[q] * cw2[q * 3 + k];
            t2[k] = lrelu(a);
        }
        #pragma unroll
        for (int k = 0; k < 3; ++k) {
            float a = 0.f;
            #pragma unroll
            for (int q = 0; q < 3; ++q) a += t2[q] * cw3[q * 3 + k];
            o[(size_t)r * 3 + k] = a;
        }
    }
}

// ---------------------------------------------------------------------------
extern "C" void kernel_launch(void* const* d_in, const int* in_sizes, int n_in,
                              void* d_out, int out_size, void* d_ws, size_t ws_size,
                              hipStream_t stream) {
    const int* elem_conn = (const int*)d_in[1];
    const int* edge_index = (const int*)d_in[2];
    const int* e_src = edge_index;          // row 0
    const int* e_dst = edge_index + NEDGE;  // row 1
    const float* enc_clnb = (const float*)d_in[9];
    const float* enc_ew1 = (const float*)d_in[10];
    const float* enc_eb1 = (const float*)d_in[11];
    const float* enc_ew2 = (const float*)d_in[12];
    const float* enc_eb2 = (const float*)d_in[13];
    const float* enc_ew3 = (const float*)d_in[14];
    const float* enc_elng = (const float*)d_in[15];
    const float* enc_elnb = (const float*)d_in[16];
    const float* p_ew1 = (const float*)d_in[17];
    const float* p_eb1 = (const float*)d_in[18];
    const float* p_ew2 = (const float*)d_in[19];
    const float* p_eb2 = (const float*)d_in[20];
    const float* p_ew3 = (const float*)d_in[21];
    const float* p_elng = (const float*)d_in[22];
    const float* p_elnb = (const float*)d_in[23];
    const float* p_nw1 = (const float*)d_in[24];
    const float* p_nb1 = (const float*)d_in[25];
    const float* p_nw2 = (const float*)d_in[26];
    const float* p_nb2 = (const float*)d_in[27];
    const float* p_nw3 = (const float*)d_in[28];
    const float* p_nlng = (const float*)d_in[29];
    const float* p_nlnb = (const float*)d_in[30];
    const float* dec_uw1 = (const float*)d_in[31];
    const float* dec_ub1 = (const float*)d_in[32];
    const float* dec_uw2 = (const float*)d_in[33];
    const float* dec_ub2 = (const float*)d_in[34];
    const float* dec_uw3 = (const float*)d_in[35];
    const float* dec_ulng = (const float*)d_in[36];
    const float* dec_ulnb = (const float*)d_in[37];
    const float* dec_cw1 = (const float*)d_in[38];
    const float* dec_cb1 = (const float*)d_in[39];
    const float* dec_cw2 = (const float*)d_in[40];
    const float* dec_cb2 = (const float*)d_in[41];
    const float* dec_cw3 = (const float*)d_in[42];

    // Workspace layout (bytes), ~72.1 MB total:
    char* ws = (char*)d_ws;
    f16*   h16     = (f16*)(ws);                        //  9,830,400
    f16*   wbuf    = (f16*)(ws + 9830400);              //  1,572,864
    float* hv0     = (float*)(ws + 11403264);           //  512
    float* m0      = (float*)(ws + 11403776);           //  512
    f16*   P1      = (f16*)(ws + 11404288);             //  9,830,400
    f16*   P2      = (f16*)(ws + 21234688);             //  9,830,400
    f16*   msg     = (f16*)(ws + 31065088);             // 39,321,600
    f16*   uval    = (f16*)(ws + 31065088);             // overlays msg (39.3MB)
    int*   deg     = (int*)(ws + 70386688);             //  153,600
    int*   rowptr  = (int*)(ws + 70540288);             //  153,600
    int*   cursor  = (int*)(ws + 70693888);             //  153,600
    int*   bsum    = (int*)(ws + 70847488);             //  1,024
    int*   dsorted = (int*)(ws + 70848512);             //  614,400
    int*   ssorted = (int*)(ws + 71462912);             //  614,400
    // Mesh CSR overlays `cursor` (dead after csr_scatter): 139,264 <= 153,600
    int*   mdeg    = (int*)(ws + 70693888);             //  20,480 (NNP)
    int*   mrow    = (int*)(ws + 70714368);             //  20,480
    int*   mcur    = (int*)(ws + 70734848);             //  20,480
    int*   mbsum   = (int*)(ws + 70755328);             //  1,024
    int*   mslot   = (int*)(ws + 70756352);             //  76,800
    // Transposed decoder weights overlay P1 (dead after last gn_edge)
    float* dwt     = (float*)P1;                        //  26,624

    // ---- Encoder constants + weight conversion
    enc_const_kernel<<<1, 128, 0, stream>>>(enc_clnb, enc_ew1, enc_eb1, enc_ew2,
                                            enc_eb2, enc_ew3, enc_elng, enc_elnb, hv0);
    init_h16_kernel<<<1200, 256, 0, stream>>>(h16, hv0, NTOT * HD / 8);
    conv_weights_kernel<<<48, 256, 0, stream>>>(p_ew1, p_ew2, p_ew3,
                                                p_nw1, p_nw2, p_nw3, wbuf);
    msg0_kernel<<<1, 128, 0, stream>>>(hv0, p_ew1, p_eb1, p_ew2, p_eb2, p_ew3,
                                       p_elng, p_elnb, m0);

    // ---- Edge CSR build (edge_index constant; rebuilt every call)
    hipMemsetAsync(deg, 0, NTOT * sizeof(int), stream);
    hipMemsetAsync(cursor, 0, NTOT * sizeof(int), stream);
    csr_hist<<<NEDGE / 256, 256, 0, stream>>>(e_dst, deg, NEDGE);
    csr_scan1<<<NTOT / 256, 256, 0, stream>>>(deg, rowptr, bsum);
    csr_scan2<<<1, 256, 0, stream>>>(bsum, NTOT / 256);
    csr_scan3<<<NTOT / 256, 256, 0, stream>>>(rowptr, bsum);
    csr_scatter<<<NEDGE / 256, 256, 0, stream>>>(e_dst, e_src, rowptr, cursor,
                                                 dsorted, ssorted);

    // ---- Mesh CSR build (elem_conn constant, shared across batches).
    hipMemsetAsync(mdeg, 0, NNP * sizeof(int), stream);
    hipMemsetAsync(mcur, 0, NNP * sizeof(int), stream);
    csr_hist<<<(NE * 4 + 255) / 256, 256, 0, stream>>>(elem_conn, mdeg, NE * 4);
    csr_scan1<<<NNP / 256, 256, 0, stream>>>(mdeg, mrow, mbsum);
    csr_scan2<<<1, 256, 0, stream>>>(mbsum, NNP / 256);
    csr_scan3<<<NNP / 256, 256, 0, stream>>>(mrow, mbsum);
    mesh_scatter<<<(NE * 4 + 255) / 256, 256, 0, stream>>>(elem_conn, mrow, mcur,
                                                           mslot, NE * 4);

    // ---- d=0: aggr = deg*m0 (exact); node + produce P for d=1
    {
        const f16* wd = wbuf;                       // d=0
        const f16* wn = wbuf + (size_t)8 * HD * HD; // d=1
        gn_node<0, true><<<NTOT / 64, 256, 0, stream>>>(
            h16, nullptr, nullptr, deg, m0,
            wd + 4 * HD * HD, wd + 5 * HD * HD, wd + 6 * HD * HD, wd + 7 * HD * HD,
            p_nb1, p_nb2, p_nlng, p_nlnb,
            wn + 0 * HD * HD, wn + 1 * HD * HD, P1, P2);
    }

    // ---- d=1..5
    for (int d = 1; d < DBLK; ++d) {
        const f16* wd = wbuf + (size_t)d * 8 * HD * HD;
        gn_edge<<<NEDGE / EM, 512, 0, stream>>>(
            P1, P2, dsorted, ssorted,
            wd + 2 * HD * HD, wd + 3 * HD * HD,
            p_eb1 + (size_t)d * HD, p_eb2 + (size_t)d * HD,
            p_elng + (size_t)d * HD, p_elnb + (size_t)d * HD, msg);
        if (d < DBLK - 1) {
            const f16* wn = wbuf + (size_t)(d + 1) * 8 * HD * HD;
            gn_node<1, true><<<NTOT / 64, 256, 0, stream>>>(
                h16, msg, rowptr, deg, nullptr,
                wd + 4 * HD * HD, wd + 5 * HD * HD, wd + 6 * HD * HD, wd + 7 * HD * HD,
                p_nb1 + (size_t)d * HD, p_nb2 + (size_t)d * HD,
                p_nlng + (size_t)d * HD, p_nlnb + (size_t)d * HD,
                wn + 0 * HD * HD, wn + 1 * HD * HD, P1, P2);
        } else {
            gn_node<1, false><<<NTOT / 64, 256, 0, stream>>>(
                h16, msg, rowptr, deg, nullptr,
                wd + 4 * HD * HD, wd + 5 * HD * HD, wd + 6 * HD * HD, wd + 7 * HD * HD,
                p_nb1 + (size_t)d * HD, p_nb2 + (size_t)d * HD,
                p_nlng + (size_t)d * HD, p_nlnb + (size_t)d * HD,
                wbuf, wbuf, P1, P2);
        }
    }

    // ---- Decoder: transposed weights into dead P1 region, then no-atomic
    // store + gather. uval overlays msg (dead after last gn_node).
    conv_dec_weights<<<1, 256, 0, stream>>>(dec_uw1, dec_ub1, dec_uw2, dec_ub2,
                                            dec_uw3, dec_ulng, dec_ulnb, dwt);
    dec_store_kernel<<<NTOT * HD / 256, 256, 0, stream>>>(h16, dwt, uval);
    dec_gather_out<<<(NMESH + 3) / 4, 256, 0, stream>>>(
        uval, mrow, mdeg, mslot, dec_cw1, dec_cb1, dec_cw2, dec_cb2, dec_cw3,
        (float*)d_out, NMESH);
}

// Round 15
// 639.985 us; speedup vs baseline: 1.0383x; 1.0383x over previous
//
#include <hip/hip_runtime.h>
#include <hip/hip_fp16.h>
#include <math.h>

// Problem constants (from reference)
#define BS    8
#define NE    4800
#define NN    4981
#define CIN   3
#define HD    128      // H
#define DBLK  6        // D processor blocks
#define NEDGE 153600   // BS*EPG
#define NTOT  38400    // BS*NE (graph nodes)
#define NMESH (BS*NN)  // 39848 mesh rows
#define NNP   5120     // NN padded to 20*256 for scan
#define EM    128      // edge-kernel tile rows

// transposed decoder-weight table offsets (floats)
#define UW1T  0
#define UB1T  512
#define UW2T  1024
#define UB2T  3072
#define UW3T  3584
#define ULNGT 5632
#define ULNBT 6144
#define DWT_N 6656

typedef _Float16 f16;
typedef _Float16 f16x8 __attribute__((ext_vector_type(8)));
typedef float f32x4 __attribute__((ext_vector_type(4)));

__device__ __forceinline__ float lrelu(float x) { return x >= 0.0f ? x : 0.2f * x; }

// ---------------------------------------------------------------------------
// K0: hv0 = ln(mlp(enc_clnb_row, enc_ew1..3), enc_elng, enc_elnb)
// Conv encoder + LayerNorm over size-1 axis collapses exactly to enc_clnb.
// ---------------------------------------------------------------------------
__global__ __launch_bounds__(128)
void enc_const_kernel(const float* __restrict__ clnb,
                      const float* __restrict__ ew1, const float* __restrict__ eb1,
                      const float* __restrict__ ew2, const float* __restrict__ eb2,
                      const float* __restrict__ ew3,
                      const float* __restrict__ g, const float* __restrict__ b,
                      float* __restrict__ hv0) {
    __shared__ float s1[HD], s2[HD], s3[HD];
    int j = threadIdx.x;
    float a = eb1[j];
    for (int c = 0; c < CIN; ++c) a += clnb[c] * ew1[c * HD + j];
    s1[j] = lrelu(a);
    __syncthreads();
    a = eb2[j];
    for (int k = 0; k < HD; ++k) a += s1[k] * ew2[k * HD + j];
    s2[j] = lrelu(a);
    __syncthreads();
    a = 0.0f;
    for (int k = 0; k < HD; ++k) a += s2[k] * ew3[k * HD + j];
    s3[j] = a;
    __syncthreads();
    float m = 0.0f;
    for (int k = 0; k < HD; ++k) m += s3[k];
    m *= (1.0f / HD);
    float v = 0.0f;
    for (int k = 0; k < HD; ++k) { float d = s3[k] - m; v += d * d; }
    v *= (1.0f / HD);
    float rs = 1.0f / sqrtf(v + 1e-5f);
    hv0[j] = (s3[j] - m) * rs * g[j] + b[j];
}

// d=0 edge message: m0 = ln(mlp([h0;h0]), elng0, elnb0). Exact identity:
// at d=0 all node rows equal h0 -> every edge message equals m0 and
// aggr[n] = deg(n) * m0.
__global__ __launch_bounds__(128)
void msg0_kernel(const float* __restrict__ hv0,
                 const float* __restrict__ ew1, const float* __restrict__ eb1,
                 const float* __restrict__ ew2, const float* __restrict__ eb2,
                 const float* __restrict__ ew3,
                 const float* __restrict__ g, const float* __restrict__ b,
                 float* __restrict__ m0) {
    __shared__ float s1[HD], s2[HD], s3[HD];
    int j = threadIdx.x;
    float a = eb1[j];
    for (int k = 0; k < HD; ++k) a += hv0[k] * (ew1[k * HD + j] + ew1[(k + HD) * HD + j]);
    s1[j] = lrelu(a);
    __syncthreads();
    a = eb2[j];
    for (int k = 0; k < HD; ++k) a += s1[k] * ew2[k * HD + j];
    s2[j] = lrelu(a);
    __syncthreads();
    a = 0.0f;
    for (int k = 0; k < HD; ++k) a += s2[k] * ew3[k * HD + j];
    s3[j] = a;
    __syncthreads();
    float m = 0.0f;
    for (int k = 0; k < HD; ++k) m += s3[k];
    m *= (1.0f / HD);
    float v = 0.0f;
    for (int k = 0; k < HD; ++k) { float d = s3[k] - m; v += d * d; }
    v *= (1.0f / HD);
    float rs = 1.0f / sqrtf(v + 1e-5f);
    m0[j] = (s3[j] - m) * rs * g[j] + b[j];
}

// Broadcast hv0 (fp32) to all NTOT node rows as f16
__global__ __launch_bounds__(256)
void init_h16_kernel(f16* __restrict__ h, const float* __restrict__ hv0, int n8) {
    __shared__ f16 v[HD];
    if (threadIdx.x < HD) v[threadIdx.x] = (f16)hv0[threadIdx.x];
    __syncthreads();
    for (int i = blockIdx.x * blockDim.x + threadIdx.x; i < n8; i += gridDim.x * blockDim.x)
        ((uint4*)h)[i] = ((const uint4*)v)[i & 15];
}

// ---------------------------------------------------------------------------
// Convert + transpose processor weights to f16 Wt[n][k] layout.
// ---------------------------------------------------------------------------
__global__ __launch_bounds__(256)
void conv_weights_kernel(const float* __restrict__ ew1, const float* __restrict__ ew2,
                         const float* __restrict__ ew3,
                         const float* __restrict__ nw1, const float* __restrict__ nw2,
                         const float* __restrict__ nw3, f16* __restrict__ wbuf) {
    int b = blockIdx.x;        // 0..47
    int d = b >> 3, m = b & 7;
    const float* src;
    switch (m) {
        case 0: src = ew1 + (size_t)d * 2 * HD * HD; break;
        case 1: src = ew1 + (size_t)d * 2 * HD * HD + HD * HD; break;
        case 2: src = ew2 + (size_t)d * HD * HD; break;
        case 3: src = ew3 + (size_t)d * HD * HD; break;
        case 4: src = nw1 + (size_t)d * 2 * HD * HD; break;
        case 5: src = nw1 + (size_t)d * 2 * HD * HD + HD * HD; break;
        case 6: src = nw2 + (size_t)d * HD * HD; break;
        default: src = nw3 + (size_t)d * HD * HD; break;
    }
    f16* out = wbuf + (size_t)b * HD * HD;
    for (int idx = threadIdx.x; idx < HD * HD; idx += 256) {
        int n = idx >> 7, k = idx & 127;
        out[idx] = (f16)src[k * HD + n];   // Wt[n][k] = W[k][n]
    }
}

// f16 copy of the edge L1 biases (6 layers x 128) for the packed-f16 act1.
__global__ __launch_bounds__(256)
void conv_ebias_kernel(const float* __restrict__ eb1, f16* __restrict__ eb16) {
    for (int i = threadIdx.x; i < DBLK * HD; i += 256)
        eb16[i] = (f16)eb1[i];
}

// Transpose decoder per-channel weights to channel-major (lane-coalesced).
__global__ __launch_bounds__(256)
void conv_dec_weights(const float* __restrict__ uw1, const float* __restrict__ ub1,
                      const float* __restrict__ uw2, const float* __restrict__ ub2,
                      const float* __restrict__ uw3, const float* __restrict__ ulng,
                      const float* __restrict__ ulnb, float* __restrict__ dwt) {
    int tid = threadIdx.x;
    for (int idx = tid; idx < 512; idx += 256) {
        int o = idx >> 7, c = idx & 127;
        dwt[UW1T + idx] = uw1[c * 4 + o];
        dwt[UB1T + idx] = ub1[c * 4 + o];
        dwt[UB2T + idx] = ub2[c * 4 + o];
        dwt[ULNGT + idx] = ulng[c * 4 + o];
        dwt[ULNBT + idx] = ulnb[c * 4 + o];
    }
    for (int idx = tid; idx < 2048; idx += 256) {
        int io = idx >> 7, c = idx & 127;
        dwt[UW2T + idx] = uw2[c * 16 + io];
        dwt[UW3T + idx] = uw3[c * 16 + io];
    }
}

// ---------------------------------------------------------------------------
// CSR build helpers (counting sort). Edge graph (by dest) + mesh (by conn).
// ---------------------------------------------------------------------------
__global__ __launch_bounds__(256)
void csr_hist(const int* __restrict__ key, int* __restrict__ deg, int n) {
    int e = blockIdx.x * 256 + threadIdx.x;
    if (e < n) atomicAdd(&deg[key[e]], 1);
}

__global__ __launch_bounds__(256)
void csr_scan1(const int* __restrict__ deg, int* __restrict__ rowptr,
               int* __restrict__ bsum) {
    __shared__ int s[256];
    int i = blockIdx.x * 256 + threadIdx.x;
    int v = deg[i];
    s[threadIdx.x] = v;
    __syncthreads();
    for (int off = 1; off < 256; off <<= 1) {
        int t = (threadIdx.x >= off) ? s[threadIdx.x - off] : 0;
        __syncthreads();
        s[threadIdx.x] += t;
        __syncthreads();
    }
    rowptr[i] = s[threadIdx.x] - v;          // exclusive
    if (threadIdx.x == 255) bsum[blockIdx.x] = s[255];
}

__global__ __launch_bounds__(256)
void csr_scan2(int* __restrict__ bsum, int nb) {
    __shared__ int s[256];
    int v = (threadIdx.x < nb) ? bsum[threadIdx.x] : 0;
    s[threadIdx.x] = v;
    __syncthreads();
    for (int off = 1; off < 256; off <<= 1) {
        int t = (threadIdx.x >= off) ? s[threadIdx.x - off] : 0;
        __syncthreads();
        s[threadIdx.x] += t;
        __syncthreads();
    }
    if (threadIdx.x < nb) bsum[threadIdx.x] = s[threadIdx.x] - v;   // exclusive
}

__global__ __launch_bounds__(256)
void csr_scan3(int* __restrict__ rowptr, const int* __restrict__ bsum) {
    int i = blockIdx.x * 256 + threadIdx.x;
    rowptr[i] += bsum[blockIdx.x];
}

// Edge scatter: store (dest, src) sorted by dest
__global__ __launch_bounds__(256)
void csr_scatter(const int* __restrict__ dest, const int* __restrict__ srcv,
                 const int* __restrict__ rowptr, int* __restrict__ cursor,
                 int* __restrict__ dsorted, int* __restrict__ ssorted) {
    int e = blockIdx.x * 256 + threadIdx.x;
    int d = dest[e];
    int pos = rowptr[d] + atomicAdd(&cursor[d], 1);
    dsorted[pos] = d;
    ssorted[pos] = srcv[e];
}

// Mesh scatter: store slot index (e*4+o) sorted by mesh node conn[e*4+o]
__global__ __launch_bounds__(256)
void mesh_scatter(const int* __restrict__ conn, const int* __restrict__ mrow,
                  int* __restrict__ mcur, int* __restrict__ mslot, int n) {
    int idx = blockIdx.x * 256 + threadIdx.x;
    if (idx < n) {
        int nd = conn[idx];
        int pos = mrow[nd] + atomicAdd(&mcur[nd], 1);
        mslot[pos] = idx;
    }
}

// ---------------------------------------------------------------------------
// Shared GEMM helpers. MFMA 16x16x32; wave w: rows (w>>1)*32, cols (w&1)*64,
// 2x4 grid of tiles. A[m=lane&15][k=quad*8+j], C/D col=lane&15, row=quad*4+reg
// (guide-verified).
// ---------------------------------------------------------------------------
template <int NT>
__device__ __forceinline__ void stage_w(const f16* __restrict__ Wg, f16 (*Bt)[HD + 8],
                                        int tid) {
    #pragma unroll
    for (int t = 0; t < 2048 / NT; ++t) {
        int idx = tid + t * NT;             // 16B chunks of 128x128 f16
        int r = idx >> 4, c = (idx & 15) * 8;
        *(uint4*)(&Bt[r][c]) = *(const uint4*)(Wg + (size_t)r * HD + c);
    }
}

__device__ __forceinline__ void mfma_pass(const f16 (*A)[HD + 8], const f16 (*Bt)[HD + 8],
                                          int rt_base, int ct_base, int ln, int quad,
                                          f32x4 acc[2][4]) {
    #pragma unroll
    for (int ks = 0; ks < 4; ++ks) {
        int kb = ks * 32 + quad * 8;
        f16x8 a0 = *(const f16x8*)(&A[rt_base + ln][kb]);
        f16x8 a1 = *(const f16x8*)(&A[rt_base + 16 + ln][kb]);
        #pragma unroll
        for (int c = 0; c < 4; ++c) {
            f16x8 b = *(const f16x8*)(&Bt[ct_base + c * 16 + ln][kb]);
            acc[0][c] = __builtin_amdgcn_mfma_f32_16x16x32_f16(a0, b, acc[0][c], 0, 0, 0);
            acc[1][c] = __builtin_amdgcn_mfma_f32_16x16x32_f16(a1, b, acc[1][c], 0, 0, 0);
        }
    }
}

// ---------------------------------------------------------------------------
// Edge kernel (d>=1), dest-sorted, M=128 tile, 512 threads (8 waves):
// act1 = lrelu(P1[d]+P2[s]+b1) computed in PACKED f16 (v_pk_add/mul/max:
// lrelu(x) = max(x, 0.2x), exact for both signs) — cuts the act1 VALU chain
// ~4x vs the f32 convert path (VALUBusy was 33%, the largest pipe).
// W2/W3 passes, LN, plain f16 store to msg. Full-K Bt staging, 2 blocks/CU —
// measured local optimum (rounds 10-14; noise band +-3.5%).
// ---------------------------------------------------------------------------
__global__ __launch_bounds__(512, 4)
void gn_edge(const f16* __restrict__ P1, const f16* __restrict__ P2,
             const int* __restrict__ dsorted, const int* __restrict__ ssorted,
             const f16* __restrict__ W2, const f16* __restrict__ W3,
             const f16* __restrict__ b1h, const float* __restrict__ b2,
             const float* __restrict__ g, const float* __restrict__ bln,
             f16* __restrict__ msg) {
    __shared__ __align__(16) f16 As[EM][HD + 8];
    __shared__ __align__(16) f16 Bt[HD][HD + 8];
    __shared__ float red[EM][2][2];
    __shared__ int dS[EM], sS[EM];

    const int tid = threadIdx.x;
    const int base = blockIdx.x * EM;
    const int wave = tid >> 6, lane = tid & 63;
    const int ln = lane & 15, quad = lane >> 4;
    const int rt_base = (wave >> 1) * 32;     // 0,32,64,96
    const int ct_base = (wave & 1) * 64;
    const int half = wave & 1;

    if (tid < EM) dS[tid] = dsorted[base + tid];
    else if (tid < 2 * EM) sS[tid - EM] = ssorted[base + tid - EM];
    __syncthreads();

    const f16 k02s = (f16)0.2f;
    const f16x8 k02 = {k02s, k02s, k02s, k02s, k02s, k02s, k02s, k02s};

    stage_w<512>(W2, Bt, tid);
    #pragma unroll
    for (int t = 0; t < 4; ++t) {
        int idx = tid + t * 512;            // 0..2047
        int r = idx >> 4, c = (idx & 15) * 8;
        f16x8 p1 = *(const f16x8*)(P1 + (size_t)dS[r] * HD + c);
        f16x8 p2 = *(const f16x8*)(P2 + (size_t)sS[r] * HD + c);
        f16x8 bb = *(const f16x8*)(b1h + c);
        f16x8 s = p1 + p2 + bb;             // v_pk_add_f16
        f16x8 o = __builtin_elementwise_max(s, s * k02);  // packed lrelu
        *(f16x8*)(&As[r][c]) = o;
    }
    __syncthreads();

    f32x4 acc[2][4];

    // ---- Layer 2
    #pragma unroll
    for (int c = 0; c < 4; ++c) {
        float bj = b2[ct_base + c * 16 + ln];
        f32x4 bb = {bj, bj, bj, bj};
        acc[0][c] = bb; acc[1][c] = bb;
    }
    mfma_pass(As, Bt, rt_base, ct_base, ln, quad, acc);
    __syncthreads();
    stage_w<512>(W3, Bt, tid);
    #pragma unroll
    for (int i = 0; i < 2; ++i)
        #pragma unroll
        for (int c = 0; c < 4; ++c)
            #pragma unroll
            for (int r = 0; r < 4; ++r)
                As[rt_base + i * 16 + quad * 4 + r][ct_base + c * 16 + ln] =
                    (f16)lrelu(acc[i][c][r]);
    __syncthreads();

    // ---- Layer 3
    #pragma unroll
    for (int c = 0; c < 4; ++c) { f32x4 z = {0,0,0,0}; acc[0][c] = z; acc[1][c] = z; }
    mfma_pass(As, Bt, rt_base, ct_base, ln, quad, acc);

    // ---- LayerNorm stats
    #pragma unroll
    for (int i = 0; i < 2; ++i)
        #pragma unroll
        for (int r = 0; r < 4; ++r) {
            float s = acc[i][0][r] + acc[i][1][r] + acc[i][2][r] + acc[i][3][r];
            float q = acc[i][0][r] * acc[i][0][r] + acc[i][1][r] * acc[i][1][r] +
                      acc[i][2][r] * acc[i][2][r] + acc[i][3][r] * acc[i][3][r];
            s += __shfl_xor(s, 1); q += __shfl_xor(q, 1);
            s += __shfl_xor(s, 2); q += __shfl_xor(q, 2);
            s += __shfl_xor(s, 4); q += __shfl_xor(q, 4);
            s += __shfl_xor(s, 8); q += __shfl_xor(q, 8);
            if (ln == 0) {
                int row = rt_base + i * 16 + quad * 4 + r;
                red[row][half][0] = s;
                red[row][half][1] = q;
            }
        }
    __syncthreads();

    // ---- Epilogue: LN scale + plain f16 store to msg (sorted slot order)
    float gv[4], bv[4];
    #pragma unroll
    for (int c = 0; c < 4; ++c) {
        int col = ct_base + c * 16 + ln;
        gv[c] = g[col]; bv[c] = bln[col];
    }
    #pragma unroll
    for (int i = 0; i < 2; ++i)
        #pragma unroll
        for (int r = 0; r < 4; ++r) {
            int row = rt_base + i * 16 + quad * 4 + r;
            float s = red[row][0][0] + red[row][1][0];
            float q = red[row][0][1] + red[row][1][1];
            float m = s * (1.0f / HD);
            float var = q * (1.0f / HD) - m * m;
            float rs = 1.0f / sqrtf(var + 1e-5f);
            #pragma unroll
            for (int c = 0; c < 4; ++c) {
                int col = ct_base + c * 16 + ln;
                float v = (acc[i][c][r] - m) * rs * gv[c] + bv[c];
                msg[(size_t)(base + row) * HD + col] = (f16)v;
            }
        }
}

// ---------------------------------------------------------------------------
// Node kernel — single 64-row As buffer, h held in VGPRs during the aggr
// pass (L1 split passes reordered: aggr@W1b then h@W1a — commutative).
// rpS/dgS alias `red`. LDS 54.3 KB -> 3 blocks/CU.
// AGGR=0: aggr row = deg(n)*m0 (exact d=0 identity).
// AGGR=1: aggr row = fp32 sum of the node's contiguous msg rows (CSR).
// PROD: also emit P1/P2 for the next edge stage. In-place h16 update.
// ---------------------------------------------------------------------------
template <int AGGR, bool PROD>
__global__ __launch_bounds__(256, 3)
void gn_node(f16* __restrict__ h16, const f16* __restrict__ msg,
             const int* __restrict__ rowptr, const int* __restrict__ deg,
             const float* __restrict__ m0,
             const f16* __restrict__ W1a, const f16* __restrict__ W1b,
             const f16* __restrict__ W2, const f16* __restrict__ W3,
             const float* __restrict__ b1, const float* __restrict__ b2,
             const float* __restrict__ g, const float* __restrict__ bln,
             const f16* __restrict__ nW1a, const f16* __restrict__ nW1b,
             f16* __restrict__ P1, f16* __restrict__ P2) {
    __shared__ __align__(16) f16 As[64][HD + 8];
    __shared__ __align__(16) f16 Bt[HD][HD + 8];
    __shared__ float red[64][2][2];
    int* rpS = (int*)&red[0][0][0];   // alias: index staging only (pre-LN)
    int* dgS = rpS + 64;

    const int tid = threadIdx.x;
    const int base = blockIdx.x * 64;
    const int wave = tid >> 6, lane = tid & 63;
    const int ln = lane & 15, quad = lane >> 4;
    const int rt_base = (wave >> 1) * 32;
    const int ct_base = (wave & 1) * 64;
    const int half = wave & 1;

    if (tid < 64) {
        if (AGGR == 1) rpS[tid] = rowptr[base + tid];
        dgS[tid] = deg[base + tid];
    }
    __syncthreads();

    // ---- Stage: aggr -> As, h -> hreg (VGPRs)
    f16x8 hreg[4];
    #pragma unroll
    for (int t = 0; t < 4; ++t) {
        int idx = tid + t * 256;            // 0..1023
        int r = idx >> 4, c = (idx & 15) * 8;
        hreg[t] = *(const f16x8*)(h16 + (size_t)(base + r) * HD + c);
        if (AGGR == 0) {
            float sc = (float)dgS[r];
            f16x8 o;
            #pragma unroll
            for (int u = 0; u < 8; ++u) o[u] = (f16)(sc * m0[c + u]);
            *(f16x8*)(&As[r][c]) = o;
        } else {
            int rp = rpS[r], dg = dgS[r];
            float a[8] = {0, 0, 0, 0, 0, 0, 0, 0};
            for (int j = 0; j < dg; ++j) {
                f16x8 mv = *(const f16x8*)(msg + (size_t)(rp + j) * HD + c);
                #pragma unroll
                for (int u = 0; u < 8; ++u) a[u] += (float)mv[u];
            }
            f16x8 o;
            #pragma unroll
            for (int u = 0; u < 8; ++u) o[u] = (f16)a[u];
            *(f16x8*)(&As[r][c]) = o;
        }
    }
    stage_w<256>(W1b, Bt, tid);
    __syncthreads();

    f32x4 acc[2][4];
    #pragma unroll
    for (int c = 0; c < 4; ++c) {
        float bj = b1[ct_base + c * 16 + ln];
        f32x4 bb = {bj, bj, bj, bj};
        acc[0][c] = bb; acc[1][c] = bb;
    }
    mfma_pass(As, Bt, rt_base, ct_base, ln, quad, acc);   // aggr @ W1b
    __syncthreads();

    #pragma unroll
    for (int t = 0; t < 4; ++t) {
        int idx = tid + t * 256;
        int r = idx >> 4, c = (idx & 15) * 8;
        *(f16x8*)(&As[r][c]) = hreg[t];
    }
    stage_w<256>(W1a, Bt, tid);
    __syncthreads();
    mfma_pass(As, Bt, rt_base, ct_base, ln, quad, acc);   // + h @ W1a
    __syncthreads();

    stage_w<256>(W2, Bt, tid);
    #pragma unroll
    for (int i = 0; i < 2; ++i)
        #pragma unroll
        for (int c = 0; c < 4; ++c)
            #pragma unroll
            for (int r = 0; r < 4; ++r)
                As[rt_base + i * 16 + quad * 4 + r][ct_base + c * 16 + ln] =
                    (f16)lrelu(acc[i][c][r]);
    __syncthreads();

    #pragma unroll
    for (int c = 0; c < 4; ++c) {
        float bj = b2[ct_base + c * 16 + ln];
        f32x4 bb = {bj, bj, bj, bj};
        acc[0][c] = bb; acc[1][c] = bb;
    }
    mfma_pass(As, Bt, rt_base, ct_base, ln, quad, acc);   // act1 @ W2
    __syncthreads();
    stage_w<256>(W3, Bt, tid);
    #pragma unroll
    for (int i = 0; i < 2; ++i)
        #pragma unroll
        for (int c = 0; c < 4; ++c)
            #pragma unroll
            for (int r = 0; r < 4; ++r)
                As[rt_base + i * 16 + quad * 4 + r][ct_base + c * 16 + ln] =
                    (f16)lrelu(acc[i][c][r]);
    __syncthreads();

    #pragma unroll
    for (int c = 0; c < 4; ++c) { f32x4 z = {0,0,0,0}; acc[0][c] = z; acc[1][c] = z; }
    mfma_pass(As, Bt, rt_base, ct_base, ln, quad, acc);   // act2 @ W3

    // ---- LayerNorm stats (red now safe: rpS/dgS long dead)
    #pragma unroll
    for (int i = 0; i < 2; ++i)
        #pragma unroll
        for (int r = 0; r < 4; ++r) {
            float s = acc[i][0][r] + acc[i][1][r] + acc[i][2][r] + acc[i][3][r];
            float q = acc[i][0][r] * acc[i][0][r] + acc[i][1][r] * acc[i][1][r] +
                      acc[i][2][r] * acc[i][2][r] + acc[i][3][r] * acc[i][3][r];
            s += __shfl_xor(s, 1); q += __shfl_xor(q, 1);
            s += __shfl_xor(s, 2); q += __shfl_xor(q, 2);
            s += __shfl_xor(s, 4); q += __shfl_xor(q, 4);
            s += __shfl_xor(s, 8); q += __shfl_xor(q, 8);
            if (ln == 0) {
                int row = rt_base + i * 16 + quad * 4 + r;
                red[row][half][0] = s;
                red[row][half][1] = q;
            }
        }
    __syncthreads();

    float gv[4], bv[4];
    #pragma unroll
    for (int c = 0; c < 4; ++c) {
        int col = ct_base + c * 16 + ln;
        gv[c] = g[col]; bv[c] = bln[col];
    }
    #pragma unroll
    for (int i = 0; i < 2; ++i)
        #pragma unroll
        for (int r = 0; r < 4; ++r) {
            int row = rt_base + i * 16 + quad * 4 + r;
            float s = red[row][0][0] + red[row][1][0];
            float q = red[row][0][1] + red[row][1][1];
            float m = s * (1.0f / HD);
            float var = q * (1.0f / HD) - m * m;
            float rs = 1.0f / sqrtf(var + 1e-5f);
            #pragma unroll
            for (int c = 0; c < 4; ++c) {
                int col = ct_base + c * 16 + ln;
                float v = (acc[i][c][r] - m) * rs * gv[c] + bv[c];
                f16 hv = (f16)v;
                h16[(size_t)(base + row) * HD + col] = hv;
                if (PROD) As[row][col] = hv;    // h_new for P production
            }
        }

    if (PROD) {
        __syncthreads();                 // h_new in As visible
        stage_w<256>(nW1a, Bt, tid);
        __syncthreads();
        #pragma unroll
        for (int c = 0; c < 4; ++c) { f32x4 z = {0,0,0,0}; acc[0][c] = z; acc[1][c] = z; }
        mfma_pass(As, Bt, rt_base, ct_base, ln, quad, acc);
        #pragma unroll
        for (int i = 0; i < 2; ++i)
            #pragma unroll
            for (int c = 0; c < 4; ++c)
                #pragma unroll
                for (int r = 0; r < 4; ++r)
                    P1[(size_t)(base + rt_base + i * 16 + quad * 4 + r) * HD +
                       ct_base + c * 16 + ln] = (f16)acc[i][c][r];
        __syncthreads();
        stage_w<256>(nW1b, Bt, tid);
        __syncthreads();
        #pragma unroll
        for (int c = 0; c < 4; ++c) { f32x4 z = {0,0,0,0}; acc[0][c] = z; acc[1][c] = z; }
        mfma_pass(As, Bt, rt_base, ct_base, ln, quad, acc);
        #pragma unroll
        for (int i = 0; i < 2; ++i)
            #pragma unroll
            for (int c = 0; c < 4; ++c)
                #pragma unroll
                for (int r = 0; r < 4; ++r)
                    P2[(size_t)(base + rt_base + i * 16 + quad * 4 + r) * HD +
                       ct_base + c * 16 + ln] = (f16)acc[i][c][r];
    }
}

// ---------------------------------------------------------------------------
// Decoder stage 1: upsample MLP + LN(4) with channel-major (coalesced)
// transposed weights; LDS-staged wide stores to uval.
// ---------------------------------------------------------------------------
__global__ __launch_bounds__(256)
void dec_store_kernel(const f16* __restrict__ h, const float* __restrict__ dwt,
                      f16* __restrict__ uval) {
    __shared__ f16 ub[2][4][HD];
    int tid = threadIdx.x;
    int idx = blockIdx.x * 256 + tid;            // 0 .. NTOT*HD-1
    int c = idx & 127;
    int nl = tid >> 7;                           // 0..1
    float s = (float)h[idx];
    float u1[4], u2[4], u3[4];
    #pragma unroll
    for (int o = 0; o < 4; ++o)
        u1[o] = lrelu(s * dwt[UW1T + o * 128 + c] + dwt[UB1T + o * 128 + c]);
    #pragma unroll
    for (int o = 0; o < 4; ++o) {
        float a = dwt[UB2T + o * 128 + c];
        #pragma unroll
        for (int i = 0; i < 4; ++i) a += u1[i] * dwt[UW2T + (i * 4 + o) * 128 + c];
        u2[o] = lrelu(a);
    }
    #pragma unroll
    for (int o = 0; o < 4; ++o) {
        float a = 0.f;
        #pragma unroll
        for (int i = 0; i < 4; ++i) a += u2[i] * dwt[UW3T + (i * 4 + o) * 128 + c];
        u3[o] = a;
    }
    float m = 0.25f * (u3[0] + u3[1] + u3[2] + u3[3]);
    float var = 0.f;
    #pragma unroll
    for (int o = 0; o < 4; ++o) { float d = u3[o] - m; var += d * d; }
    var *= 0.25f;
    float rs = 1.0f / sqrtf(var + 1e-5f);
    #pragma unroll
    for (int o = 0; o < 4; ++o) {
        float val = (u3[o] - m) * rs * dwt[ULNGT + o * 128 + c] + dwt[ULNBT + o * 128 + c];
        ub[nl][o][c] = (f16)val;
    }
    __syncthreads();
    int nl2 = tid >> 7, rem = tid & 127;
    uint2 v = ((const uint2*)&ub[nl2][0][0])[rem];
    ((uint2*)(uval + (size_t)(blockIdx.x * 2 + nl2) * 4 * HD))[rem] = v;
}

// ---------------------------------------------------------------------------
// Decoder stage 2 (fused gather + output MLP): one wave per mesh row.
// ---------------------------------------------------------------------------
__global__ __launch_bounds__(256)
void dec_gather_out(const f16* __restrict__ uval,
                    const int* __restrict__ mrow, const int* __restrict__ mdeg,
                    const int* __restrict__ mslot,
                    const float* __restrict__ cw1, const float* __restrict__ cb1,
                    const float* __restrict__ cw2, const float* __restrict__ cb2,
                    const float* __restrict__ cw3,
                    float* __restrict__ o, int nrows) {
    int r = blockIdx.x * 4 + (threadIdx.x >> 6);
    if (r >= nrows) return;
    int lane = threadIdx.x & 63;
    int b = r / NN, n = r - b * NN;
    int rp = mrow[n], dg = mdeg[n];
    size_t boff = (size_t)b * NE * 4;
    float a0 = 0.f, a1 = 0.f;
    for (int j = 0; j < dg; ++j) {
        int slot = mslot[rp + j];
        const f16* up = uval + (boff + slot) * HD + lane * 2;
        a0 += (float)up[0];
        a1 += (float)up[1];
    }
    int c0 = lane * 2, c1 = lane * 2 + 1;
    float s[3];
    #pragma unroll
    for (int k = 0; k < 3; ++k)
        s[k] = a0 * cw1[c0 * 3 + k] + a1 * cw1[c1 * 3 + k];
    #pragma unroll
    for (int off = 32; off >= 1; off >>= 1) {
        s[0] += __shfl_down(s[0], off);
        s[1] += __shfl_down(s[1], off);
        s[2] += __shfl_down(s[2], off);
    }
    if (lane == 0) {
        float t1[3], t2[3];
        #pragma unroll
        for (int k = 0; k < 3; ++k) t1[k] = lrelu(s[k] + cb1[k]);
        #pragma unroll
        for (int k = 0; k < 3; ++k) {
            float a = cb2[k];
            #pragma unroll
            for (int q = 0; q < 3; ++q) a += t1[q] * cw2[q * 3 + k];
            t2[k] = lrelu(a);
        }
        #pragma unroll
        for (int k = 0; k < 3; ++k) {
            float a = 0.f;
            #pragma unroll
            for (int q = 0; q < 3; ++q) a += t2[q] * cw3[q * 3 + k];
            o[(size_t)r * 3 + k] = a;
        }
    }
}

// ---------------------------------------------------------------------------
extern "C" void kernel_launch(void* const* d_in, const int* in_sizes, int n_in,
                              void* d_out, int out_size, void* d_ws, size_t ws_size,
                              hipStream_t stream) {
    const int* elem_conn = (const int*)d_in[1];
    const int* edge_index = (const int*)d_in[2];
    const int* e_src = edge_index;          // row 0
    const int* e_dst = edge_index + NEDGE;  // row 1
    const float* enc_clnb = (const float*)d_in[9];
    const float* enc_ew1 = (const float*)d_in[10];
    const float* enc_eb1 = (const float*)d_in[11];
    const float* enc_ew2 = (const float*)d_in[12];
    const float* enc_eb2 = (const float*)d_in[13];
    const float* enc_ew3 = (const float*)d_in[14];
    const float* enc_elng = (const float*)d_in[15];
    const float* enc_elnb = (const float*)d_in[16];
    const float* p_ew1 = (const float*)d_in[17];
    const float* p_eb1 = (const float*)d_in[18];
    const float* p_ew2 = (const float*)d_in[19];
    const float* p_eb2 = (const float*)d_in[20];
    const float* p_ew3 = (const float*)d_in[21];
    const float* p_elng = (const float*)d_in[22];
    const float* p_elnb = (const float*)d_in[23];
    const float* p_nw1 = (const float*)d_in[24];
    const float* p_nb1 = (const float*)d_in[25];
    const float* p_nw2 = (const float*)d_in[26];
    const float* p_nb2 = (const float*)d_in[27];
    const float* p_nw3 = (const float*)d_in[28];
    const float* p_nlng = (const float*)d_in[29];
    const float* p_nlnb = (const float*)d_in[30];
    const float* dec_uw1 = (const float*)d_in[31];
    const float* dec_ub1 = (const float*)d_in[32];
    const float* dec_uw2 = (const float*)d_in[33];
    const float* dec_ub2 = (const float*)d_in[34];
    const float* dec_uw3 = (const float*)d_in[35];
    const float* dec_ulng = (const float*)d_in[36];
    const float* dec_ulnb = (const float*)d_in[37];
    const float* dec_cw1 = (const float*)d_in[38];
    const float* dec_cb1 = (const float*)d_in[39];
    const float* dec_cw2 = (const float*)d_in[40];
    const float* dec_cb2 = (const float*)d_in[41];
    const float* dec_cw3 = (const float*)d_in[42];

    // Workspace layout (bytes), ~72.1 MB total:
    char* ws = (char*)d_ws;
    f16*   h16     = (f16*)(ws);                        //  9,830,400
    f16*   wbuf    = (f16*)(ws + 9830400);              //  1,572,864
    float* hv0     = (float*)(ws + 11403264);           //  512
    float* m0      = (float*)(ws + 11403776);           //  512
    f16*   P1      = (f16*)(ws + 11404288);             //  9,830,400
    f16*   P2      = (f16*)(ws + 21234688);             //  9,830,400
    f16*   msg     = (f16*)(ws + 31065088);             // 39,321,600
    f16*   uval    = (f16*)(ws + 31065088);             // overlays msg (39.3MB)
    int*   deg     = (int*)(ws + 70386688);             //  153,600
    int*   rowptr  = (int*)(ws + 70540288);             //  153,600
    int*   cursor  = (int*)(ws + 70693888);             //  153,600
    int*   bsum    = (int*)(ws + 70847488);             //  1,024
    int*   dsorted = (int*)(ws + 70848512);             //  614,400
    int*   ssorted = (int*)(ws + 71462912);             //  614,400
    // Mesh CSR overlays `cursor` (dead after csr_scatter): 139,264 <= 153,600
    int*   mdeg    = (int*)(ws + 70693888);             //  20,480 (NNP)
    int*   mrow    = (int*)(ws + 70714368);             //  20,480
    int*   mcur    = (int*)(ws + 70734848);             //  20,480
    int*   mbsum   = (int*)(ws + 70755328);             //  1,024
    int*   mslot   = (int*)(ws + 70756352);             //  76,800
    // Transposed decoder weights overlay P1 (dead after last gn_edge)
    float* dwt     = (float*)P1;                        //  26,624
    // f16 edge L1 biases (6 x 128)
    f16*   eb16    = (f16*)(ws + 72077312);             //  1,536

    // ---- Encoder constants + weight conversion
    enc_const_kernel<<<1, 128, 0, stream>>>(enc_clnb, enc_ew1, enc_eb1, enc_ew2,
                                            enc_eb2, enc_ew3, enc_elng, enc_elnb, hv0);
    init_h16_kernel<<<1200, 256, 0, stream>>>(h16, hv0, NTOT * HD / 8);
    conv_weights_kernel<<<48, 256, 0, stream>>>(p_ew1, p_ew2, p_ew3,
                                                p_nw1, p_nw2, p_nw3, wbuf);
    conv_ebias_kernel<<<1, 256, 0, stream>>>(p_eb1, eb16);
    msg0_kernel<<<1, 128, 0, stream>>>(hv0, p_ew1, p_eb1, p_ew2, p_eb2, p_ew3,
                                       p_elng, p_elnb, m0);

    // ---- Edge CSR build (edge_index constant; rebuilt every call)
    hipMemsetAsync(deg, 0, NTOT * sizeof(int), stream);
    hipMemsetAsync(cursor, 0, NTOT * sizeof(int), stream);
    csr_hist<<<NEDGE / 256, 256, 0, stream>>>(e_dst, deg, NEDGE);
    csr_scan1<<<NTOT / 256, 256, 0, stream>>>(deg, rowptr, bsum);
    csr_scan2<<<1, 256, 0, stream>>>(bsum, NTOT / 256);
    csr_scan3<<<NTOT / 256, 256, 0, stream>>>(rowptr, bsum);
    csr_scatter<<<NEDGE / 256, 256, 0, stream>>>(e_dst, e_src, rowptr, cursor,
                                                 dsorted, ssorted);

    // ---- Mesh CSR build (elem_conn constant, shared across batches).
    hipMemsetAsync(mdeg, 0, NNP * sizeof(int), stream);
    hipMemsetAsync(mcur, 0, NNP * sizeof(int), stream);
    csr_hist<<<(NE * 4 + 255) / 256, 256, 0, stream>>>(elem_conn, mdeg, NE * 4);
    csr_scan1<<<NNP / 256, 256, 0, stream>>>(mdeg, mrow, mbsum);
    csr_scan2<<<1, 256, 0, stream>>>(mbsum, NNP / 256);
    csr_scan3<<<NNP / 256, 256, 0, stream>>>(mrow, mbsum);
    mesh_scatter<<<(NE * 4 + 255) / 256, 256, 0, stream>>>(elem_conn, mrow, mcur,
                                                           mslot, NE * 4);

    // ---- d=0: aggr = deg*m0 (exact); node + produce P for d=1
    {
        const f16* wd = wbuf;                       // d=0
        const f16* wn = wbuf + (size_t)8 * HD * HD; // d=1
        gn_node<0, true><<<NTOT / 64, 256, 0, stream>>>(
            h16, nullptr, nullptr, deg, m0,
            wd + 4 * HD * HD, wd + 5 * HD * HD, wd + 6 * HD * HD, wd + 7 * HD * HD,
            p_nb1, p_nb2, p_nlng, p_nlnb,
            wn + 0 * HD * HD, wn + 1 * HD * HD, P1, P2);
    }

    // ---- d=1..5
    for (int d = 1; d < DBLK; ++d) {
        const f16* wd = wbuf + (size_t)d * 8 * HD * HD;
        gn_edge<<<NEDGE / EM, 512, 0, stream>>>(
            P1, P2, dsorted, ssorted,
            wd + 2 * HD * HD, wd + 3 * HD * HD,
            eb16 + (size_t)d * HD, p_eb2 + (size_t)d * HD,
            p_elng + (size_t)d * HD, p_elnb + (size_t)d * HD, msg);
        if (d < DBLK - 1) {
            const f16* wn = wbuf + (size_t)(d + 1) * 8 * HD * HD;
            gn_node<1, true><<<NTOT / 64, 256, 0, stream>>>(
                h16, msg, rowptr, deg, nullptr,
                wd + 4 * HD * HD, wd + 5 * HD * HD, wd + 6 * HD * HD, wd + 7 * HD * HD,
                p_nb1 + (size_t)d * HD, p_nb2 + (size_t)d * HD,
                p_nlng + (size_t)d * HD, p_nlnb + (size_t)d * HD,
                wn + 0 * HD * HD, wn + 1 * HD * HD, P1, P2);
        } else {
            gn_node<1, false><<<NTOT / 64, 256, 0, stream>>>(
                h16, msg, rowptr, deg, nullptr,
                wd + 4 * HD * HD, wd + 5 * HD * HD, wd + 6 * HD * HD, wd + 7 * HD * HD,
                p_nb1 + (size_t)d * HD, p_nb2 + (size_t)d * HD,
                p_nlng + (size_t)d * HD, p_nlnb + (size_t)d * HD,
                wbuf, wbuf, P1, P2);
        }
    }

    // ---- Decoder: transposed weights into dead P1 region, then no-atomic
    // store + gather. uval overlays msg (dead after last gn_node).
    conv_dec_weights<<<1, 256, 0, stream>>>(dec_uw1, dec_ub1, dec_uw2, dec_ub2,
                                            dec_uw3, dec_ulng, dec_ulnb, dwt);
    dec_store_kernel<<<NTOT * HD / 256, 256, 0, stream>>>(h16, dwt, uval);
    dec_gather_out<<<(NMESH + 3) / 4, 256, 0, stream>>>(
        uval, mrow, mdeg, mslot, dec_cw1, dec_cb1, dec_cw2, dec_cb2, dec_cw3,
        (float*)d_out, NMESH);
}